// Round 5
// baseline (721.172 us; speedup 1.0000x reference)
//
#include <hip/hip_runtime.h>

// Fused 3D window attention (Swin-style) + 1x1 conv for MI355X (gfx950).
// One workgroup (256 thr = 4 waves) per 4x4x4 window; 4096 windows.
// Register-slim rev (occupancy experiment), CORRECTED phase ordering:
//  - QKV split into q-pass / v-pass / k-pass (acc peak 32, not 64)
//  - k-pass is the last x reader; after b2, k slots overwrite dead x (R0)
//  - QK^T phase A (nt=2,3 -> packed regs) BEFORE phase B (nt=0,1 -> LDS
//    pieces): all k-slot reads complete before the piece write clobbers
//    the slot (round-3 bug: interleaved staging overwrote k rows 32-63)
//  - deferred softmax normalization (rinv applied to ovec at the end)
//  - exp2 with log2e folded into q scale (no per-element mul)
//  - wave-uniform anypad fast path; 3 barriers
//  - LDS 32 KB -> 5 blocks/CU exactly (160 KB); launch_bounds(256,5)
// (Resubmitted unchanged: round-4 bench was an infra failure, kernel never ran.)

#define NHEAD 8
#define HDIM 16
#define CCH 128
#define DD0 30
#define HH0 62
#define WW0 126
#define SD 7812      // HH0*WW0
#define SC 234360    // DD0*SD
#define QSCALE 0.3606737602f   // hd^-0.5 * log2(e) = 0.25 * 1.4426950409

typedef __bf16 bfx8 __attribute__((ext_vector_type(8)));
typedef float  fx4  __attribute__((ext_vector_type(4)));
typedef float  fx2  __attribute__((ext_vector_type(2)));

__device__ __forceinline__ fx4 MFMA(bfx8 a, bfx8 b, fx4 c) {
    return __builtin_amdgcn_mfma_f32_16x16x32_bf16(a, b, c, 0, 0, 0);
}
__device__ __forceinline__ fx4 fzero4() { fx4 v = {0.f, 0.f, 0.f, 0.f}; return v; }
__device__ __forceinline__ bfx8 bzero8() {
    bfx8 v;
    #pragma unroll
    for (int j = 0; j < 8; j++) v[j] = (__bf16)0.f;
    return v;
}
__device__ __forceinline__ unsigned pk2(float a, float b) {
    __bf16 ax = (__bf16)a, by = (__bf16)b;
    unsigned short ua = __builtin_bit_cast(unsigned short, ax);
    unsigned short ub = __builtin_bit_cast(unsigned short, by);
    return (unsigned)ua | ((unsigned)ub << 16);
}

// Cast weights to bf16. Row-major qkv_w[oc][c] / conv_w[o][c] IS the packed
// B-operand layout: B-frag lane reads 8 contiguous k at Bq[(n*16+kg)*8].
__global__ void prep_kernel(const float* __restrict__ qkv_w,
                            const float* __restrict__ conv_w,
                            __bf16* __restrict__ Bq, __bf16* __restrict__ Bc) {
    const int i = blockIdx.x * 256 + threadIdx.x;   // grid covers 65536 exactly
    if (i < 49152) Bq[i] = (__bf16)qkv_w[i];
    else            Bc[i - 49152] = (__bf16)conv_w[i - 49152];
}

__global__ __launch_bounds__(256, 5) void winattn_kernel(
    const float* __restrict__ x,
    const float* __restrict__ qkv_b,
    const float* __restrict__ conv_b,
    const __bf16* __restrict__ Bq,
    const __bf16* __restrict__ Bc,
    float* __restrict__ out)
{
    // 32 KB LDS:
    //  R0 [0,16K):  x-tile [64][128] -> k slots [8][64][16] -> P piece1 -> out stripes
    //  R1 [16K,32K): q slots [8][64][16] -> P piece0 staging
    __shared__ __align__(16) unsigned char lds_raw[32768];
    __bf16* R0 = (__bf16*)lds_raw;
    __bf16* R1 = (__bf16*)(lds_raw + 16384);

    const int tid  = threadIdx.x;
    const int wave = tid >> 6;
    const int lane = tid & 63;
    const int quad = lane >> 4;
    const int l15  = lane & 15;

    // XCD swizzle: blocks round-robin over 8 XCDs; give each XCD a contiguous
    // 512-window slab so W-adjacent windows (sharing lines) are L2-local.
    const int blk = blockIdx.x;
    const int wid = ((blk & 7) << 9) | (blk >> 3);
    const int Db = (wid >> 9) << 2;
    const int Hb = ((wid >> 5) & 15) << 2;
    const int Wb = (wid & 31) << 2;

    // pad-mask bit per token (token index == lane); token l = bd*16+bh*4+bw
    unsigned long long pmask;
    {
        const bool p = (Db + (lane >> 4) >= DD0) || (Hb + ((lane >> 2) & 3) >= HH0) ||
                       (Wb + (lane & 3) >= WW0);
        pmask = __ballot(p);
    }
    const bool anypad = (pmask != 0ULL);   // wave-uniform

    // ---- stage x window tile -> R0 bf16, swizzle phys_chunk = (c>>3) ^ (tok&15) ----
    {
        #pragma unroll
        for (int it = 0; it < 16; it++) {
            const int u = it * 256 + tid;          // (c, dh, wpair)
            const int wp = u & 1;
            const int dh = (u >> 1) & 15;
            const int c  = u >> 5;
            const int Dg = Db + (dh >> 2), Hg = Hb + (dh & 3);
            const bool valid = (Dg < DD0) && (Hg < HH0) && (wp == 0 || Wb < 124);
            fx2 v = {0.f, 0.f};
            if (valid) v = *(const fx2*)(x + c * SC + Dg * SD + Hg * WW0 + Wb + wp * 2);
            const int tok0 = dh * 4 + wp * 2;
            const int ch = c >> 3, cl = c & 7;
            R0[tok0 * 128 + ((ch ^ (tok0 & 15)) << 3) + cl] = (__bf16)v[0];
            const int tok1 = tok0 + 1;
            R0[tok1 * 128 + ((ch ^ (tok1 & 15)) << 3) + cl] = (__bf16)v[1];
        }
    }
    __syncthreads();   // b1

    unsigned vpk[2][4][2];   // v (head wave+4*hi) packed bf16: [hi][mt][r-pair]

    // ---- q-pass: q(w), q(w+4) -> R1 q slots (pre-scaled by 0.25*log2e) ----
    {
        fx4 acc[4][2];
        #pragma unroll
        for (int mt = 0; mt < 4; mt++)
            #pragma unroll
            for (int hi = 0; hi < 2; hi++) acc[mt][hi] = fzero4();
        #pragma unroll
        for (int ks = 0; ks < 4; ks++) {
            bfx8 a[4];
            #pragma unroll
            for (int mt = 0; mt < 4; mt++) {
                const int m = mt * 16 + l15;
                const int phys = (ks * 4 + quad) ^ (m & 15);
                a[mt] = *(const bfx8*)(R0 + m * 128 + phys * 8);
            }
            #pragma unroll
            for (int hi = 0; hi < 2; hi++) {
                const int col = (wave + hi * 4) * 16 + l15;
                const bfx8 bb = *(const bfx8*)(Bq + (col * 16 + ks * 4 + quad) * 8);
                #pragma unroll
                for (int mt = 0; mt < 4; mt++) acc[mt][hi] = MFMA(a[mt], bb, acc[mt][hi]);
            }
        }
        // q -> R1 slots (R1 untouched by staging: no barrier needed)
        #pragma unroll
        for (int hi = 0; hi < 2; hi++) {
            const int hh = wave + hi * 4;
            const float bias = qkv_b[hh * 16 + l15];
            #pragma unroll
            for (int mt = 0; mt < 4; mt++)
                #pragma unroll
                for (int r = 0; r < 4; r++) {
                    const int tok = mt * 16 + quad * 4 + r;
                    const int phys = (l15 >> 3) ^ ((tok >> 2) & 1);
                    R1[hh * 1024 + tok * 16 + phys * 8 + (l15 & 7)] =
                        (__bf16)((acc[mt][hi][r] + bias) * QSCALE);
                }
        }
    }

    // ---- v-pass: v(w), v(w+4) -> vpk registers ----
    {
        fx4 acc[4][2];
        #pragma unroll
        for (int mt = 0; mt < 4; mt++)
            #pragma unroll
            for (int hi = 0; hi < 2; hi++) acc[mt][hi] = fzero4();
        #pragma unroll
        for (int ks = 0; ks < 4; ks++) {
            bfx8 a[4];
            #pragma unroll
            for (int mt = 0; mt < 4; mt++) {
                const int m = mt * 16 + l15;
                const int phys = (ks * 4 + quad) ^ (m & 15);
                a[mt] = *(const bfx8*)(R0 + m * 128 + phys * 8);
            }
            #pragma unroll
            for (int hi = 0; hi < 2; hi++) {
                const int col = 256 + (wave + hi * 4) * 16 + l15;
                const bfx8 bb = *(const bfx8*)(Bq + (col * 16 + ks * 4 + quad) * 8);
                #pragma unroll
                for (int mt = 0; mt < 4; mt++) acc[mt][hi] = MFMA(a[mt], bb, acc[mt][hi]);
            }
        }
        #pragma unroll
        for (int hi = 0; hi < 2; hi++) {
            const float bias = qkv_b[256 + (wave + hi * 4) * 16 + l15];
            #pragma unroll
            for (int mt = 0; mt < 4; mt++) {
                vpk[hi][mt][0] = pk2(acc[mt][hi][0] + bias, acc[mt][hi][1] + bias);
                vpk[hi][mt][1] = pk2(acc[mt][hi][2] + bias, acc[mt][hi][3] + bias);
            }
        }
    }

    // ---- k-pass (last x reader): k(w), k(w+4) -> b2 -> R0 k slots ----
    {
        fx4 acc[4][2];
        #pragma unroll
        for (int mt = 0; mt < 4; mt++)
            #pragma unroll
            for (int hi = 0; hi < 2; hi++) acc[mt][hi] = fzero4();
        #pragma unroll
        for (int ks = 0; ks < 4; ks++) {
            bfx8 a[4];
            #pragma unroll
            for (int mt = 0; mt < 4; mt++) {
                const int m = mt * 16 + l15;
                const int phys = (ks * 4 + quad) ^ (m & 15);
                a[mt] = *(const bfx8*)(R0 + m * 128 + phys * 8);
            }
            #pragma unroll
            for (int hi = 0; hi < 2; hi++) {
                const int col = 128 + (wave + hi * 4) * 16 + l15;
                const bfx8 bb = *(const bfx8*)(Bq + (col * 16 + ks * 4 + quad) * 8);
                #pragma unroll
                for (int mt = 0; mt < 4; mt++) acc[mt][hi] = MFMA(a[mt], bb, acc[mt][hi]);
            }
        }
        __syncthreads();   // b2: all waves' x reads done; R0 becomes k slots
        #pragma unroll
        for (int hi = 0; hi < 2; hi++) {
            const int hh = wave + hi * 4;
            const float bias = qkv_b[128 + hh * 16 + l15];
            #pragma unroll
            for (int mt = 0; mt < 4; mt++)
                #pragma unroll
                for (int r = 0; r < 4; r++) {
                    const int tok = mt * 16 + quad * 4 + r;
                    const int phys = (l15 >> 3) ^ ((tok >> 2) & 1);
                    R0[hh * 1024 + tok * 16 + phys * 8 + (l15 & 7)] =
                        (__bf16)(acc[mt][hi][r] + bias);
                }
        }
    }
    // NO b3: q/k slots are wave-private; same-wave DS ops are in-order.

    // ---- attention: wave w handles heads w and w+4 (fully wave-private) ----
    // Phase A: nt=2,3 -> packed regs (k rows 32-63 consumed). Phase B: nt=0,1
    // -> LDS pieces (k rows 0-31 read before the kk piece write). PV half0,
    // stage pkS, PV half1. Deferred normalization on ovec.
    const int srcA = ((((quad << 1) + 0) & 3) << 4) | l15;
    const int srcB = ((((quad << 1) + 1) & 3) << 4) | l15;
    #pragma unroll
    for (int hi = 0; hi < 2; hi++) {
        const int hh = wave + hi * 4;
        __bf16* qs = R1 + hh * 1024;   // q slot -> P piece 0
        __bf16* kk = R0 + hh * 1024;   // k slot -> P piece 1 -> out stripe

        // A-frag from q slot (hd=16: quads 2,3 zero); qs dead after.
        bfx8 aq[4];
        #pragma unroll
        for (int mt = 0; mt < 4; mt++) {
            aq[mt] = bzero8();
            if (quad < 2) {
                const int m = mt * 16 + l15;
                const int phys = quad ^ ((m >> 2) & 1);
                aq[mt] = *(const bfx8*)(qs + m * 16 + phys * 8);
            }
        }

        float part[4][4];
        #pragma unroll
        for (int mt = 0; mt < 4; mt++)
            #pragma unroll
            for (int r = 0; r < 4; r++) part[mt][r] = 0.f;

        unsigned pkS[2][4][2];   // packed exp P for nt=2,3

        // phase A: nt = 2,3 -> regs (ALL reads of kk rows 32-63 happen here)
        #pragma unroll
        for (int ntq = 0; ntq < 2; ntq++) {
            const int nt = 2 + ntq;
            bfx8 bk = bzero8();
            if (quad < 2) {
                const int n = nt * 16 + l15;
                const int phys = quad ^ ((n >> 2) & 1);
                bk = *(const bfx8*)(kk + n * 16 + phys * 8);
            }
            fx4 lt[4];
            #pragma unroll
            for (int mt = 0; mt < 4; mt++) lt[mt] = MFMA(aq[mt], bk, fzero4());
            const unsigned cb = (unsigned)(pmask >> (nt * 16 + l15)) & 1u;
            #pragma unroll
            for (int mt = 0; mt < 4; mt++) {
                fx4 e;
                if (anypad) {
                    #pragma unroll
                    for (int r = 0; r < 4; r++) {
                        const unsigned rb =
                            (unsigned)(pmask >> (mt * 16 + quad * 4 + r)) & 1u;
                        e[r] = (rb ^ cb) ? 0.f : __builtin_amdgcn_exp2f(lt[mt][r]);
                    }
                } else {
                    #pragma unroll
                    for (int r = 0; r < 4; r++)
                        e[r] = __builtin_amdgcn_exp2f(lt[mt][r]);
                }
                #pragma unroll
                for (int r = 0; r < 4; r++) part[mt][r] += e[r];
                pkS[ntq][mt][0] = pk2(e[0], e[1]);
                pkS[ntq][mt][1] = pk2(e[2], e[3]);
            }
        }
        // phase B: nt = 0,1 -> stage into pieces (kk read precedes kk write
        // within this phase; rows 32-63 already consumed in phase A)
        #pragma unroll
        for (int nt = 0; nt < 2; nt++) {
            bfx8 bk = bzero8();
            if (quad < 2) {
                const int n = nt * 16 + l15;
                const int phys = quad ^ ((n >> 2) & 1);
                bk = *(const bfx8*)(kk + n * 16 + phys * 8);
            }
            fx4 lt[4];
            #pragma unroll
            for (int mt = 0; mt < 4; mt++) lt[mt] = MFMA(aq[mt], bk, fzero4());
            __bf16* piece = nt ? kk : qs;
            const unsigned cb = (unsigned)(pmask >> (nt * 16 + l15)) & 1u;
            #pragma unroll
            for (int mt = 0; mt < 4; mt++) {
                fx4 e;
                if (anypad) {
                    #pragma unroll
                    for (int r = 0; r < 4; r++) {
                        const unsigned rb =
                            (unsigned)(pmask >> (mt * 16 + quad * 4 + r)) & 1u;
                        e[r] = (rb ^ cb) ? 0.f : __builtin_amdgcn_exp2f(lt[mt][r]);
                    }
                } else {
                    #pragma unroll
                    for (int r = 0; r < 4; r++)
                        e[r] = __builtin_amdgcn_exp2f(lt[mt][r]);
                }
                #pragma unroll
                for (int r = 0; r < 4; r++) {
                    part[mt][r] += e[r];
                    const int tok = mt * 16 + quad * 4 + r;
                    const int phys = (l15 >> 3) ^ ((tok >> 2) & 1);
                    piece[tok * 16 + phys * 8 + (l15 & 7)] = (__bf16)e[r];
                }
            }
        }

        fx4 ovec[4];
        #pragma unroll
        for (int mt = 0; mt < 4; mt++) ovec[mt] = fzero4();

        #pragma unroll
        for (int half = 0; half < 2; half++) {
            if (half == 1) {
                // stage nt=2,3 pieces from pkS (after PV half0 reads; in-order DS)
                #pragma unroll
                for (int ntq = 0; ntq < 2; ntq++) {
                    __bf16* piece = ntq ? kk : qs;
                    #pragma unroll
                    for (int mt = 0; mt < 4; mt++)
                        #pragma unroll
                        for (int r = 0; r < 4; r++) {
                            const unsigned pr = pkS[ntq][mt][r >> 1];
                            const unsigned short hv =
                                (r & 1) ? (unsigned short)(pr >> 16)
                                        : (unsigned short)(pr & 0xffffu);
                            const int tok = mt * 16 + quad * 4 + r;
                            const int phys = (l15 >> 3) ^ ((tok >> 2) & 1);
                            piece[tok * 16 + phys * 8 + (l15 & 7)] =
                                __builtin_bit_cast(__bf16, hv);
                        }
                }
            }
            // PV half on unnormalized P; V B-frag built by shuffles from vpk.
            // bv[j] = v[half*32 + quad*8 + j][l15]
            const unsigned a00 = (unsigned)__shfl((int)vpk[hi][half * 2 + 0][0], srcA);
            const unsigned a01 = (unsigned)__shfl((int)vpk[hi][half * 2 + 0][1], srcA);
            const unsigned a10 = (unsigned)__shfl((int)vpk[hi][half * 2 + 1][0], srcA);
            const unsigned a11 = (unsigned)__shfl((int)vpk[hi][half * 2 + 1][1], srcA);
            const unsigned b00 = (unsigned)__shfl((int)vpk[hi][half * 2 + 0][0], srcB);
            const unsigned b01 = (unsigned)__shfl((int)vpk[hi][half * 2 + 0][1], srcB);
            const unsigned b10 = (unsigned)__shfl((int)vpk[hi][half * 2 + 1][0], srcB);
            const unsigned b11 = (unsigned)__shfl((int)vpk[hi][half * 2 + 1][1], srcB);
            const bool mhi = quad >= 2;
            uint4 uv;
            uv.x = mhi ? a10 : a00;
            uv.y = mhi ? a11 : a01;
            uv.z = mhi ? b10 : b00;
            uv.w = mhi ? b11 : b01;
            const bfx8 bv = __builtin_bit_cast(bfx8, uv);
            #pragma unroll
            for (int mt = 0; mt < 4; mt++) {
                const int m = mt * 16 + l15;
                const int phys = (quad & 1) ^ ((m >> 2) & 1);
                const bfx8 ap = *(const bfx8*)(((quad >> 1) ? kk : qs) + m * 16 + phys * 8);
                ovec[mt] = MFMA(ap, bv, ovec[mt]);
            }
        }
        // row-sum reduce (over l15 lanes) + deferred normalize + stripe write.
        // Stripe for head hh overlays its own k slot (dead; wave-private).
        #pragma unroll
        for (int mt = 0; mt < 4; mt++)
            #pragma unroll
            for (int r = 0; r < 4; r++) {
                float s = part[mt][r];
                s += __shfl_xor(s, 1);
                s += __shfl_xor(s, 2);
                s += __shfl_xor(s, 4);
                s += __shfl_xor(s, 8);
                const float rinv = __builtin_amdgcn_rcpf(s);
                const int tok = mt * 16 + quad * 4 + r;
                const int phys = (l15 >> 3) ^ ((tok >> 2) & 1);
                kk[tok * 16 + phys * 8 + (l15 & 7)] = (__bf16)(ovec[mt][r] * rinv);
            }
    }
    __syncthreads();   // b4: all stripes written; R0 = attn-out [8 stripes][64][16]

    // ---- 1x1 conv: (64x128)@(128x128); wave owns 32 cols; store from C-layout ----
    {
        fx4 cacc[4][2];
        #pragma unroll
        for (int mt = 0; mt < 4; mt++)
            #pragma unroll
            for (int nt = 0; nt < 2; nt++) cacc[mt][nt] = fzero4();
        #pragma unroll
        for (int ks = 0; ks < 4; ks++) {
            const int kg = ks * 4 + quad;          // channel chunk = head stripe kg>>1
            bfx8 a[4];
            #pragma unroll
            for (int mt = 0; mt < 4; mt++) {
                const int m = mt * 16 + l15;
                const int phys = (kg & 1) ^ ((m >> 2) & 1);
                a[mt] = *(const bfx8*)(R0 + (kg >> 1) * 1024 + m * 16 + phys * 8);
            }
            #pragma unroll
            for (int nt = 0; nt < 2; nt++) {
                const int o = wave * 32 + nt * 16 + l15;
                const bfx8 bb = *(const bfx8*)(Bc + (o * 16 + kg) * 8);
                #pragma unroll
                for (int mt = 0; mt < 4; mt++) cacc[mt][nt] = MFMA(a[mt], bb, cacc[mt][nt]);
            }
        }
        // C-layout: cacc[mt][nt][r] = out[o=..][D=Db+mt][H=Hb+quad][W=Wb+r]
        #pragma unroll
        for (int nt = 0; nt < 2; nt++) {
            const int o = wave * 32 + nt * 16 + l15;
            const float cb = conv_b[o];
            #pragma unroll
            for (int mt = 0; mt < 4; mt++) {
                if (Db + mt < DD0) {
                    const int Hg = Hb + quad;
                    if (Hg < HH0) {
                        const int base = o * SC + (Db + mt) * SD + Hg * WW0 + Wb;
                        fx2 w0 = {cacc[mt][nt][0] + cb, cacc[mt][nt][1] + cb};
                        *(fx2*)(out + base) = w0;
                        if (Wb < 124) {
                            fx2 w1 = {cacc[mt][nt][2] + cb, cacc[mt][nt][3] + cb};
                            *(fx2*)(out + base + 2) = w1;
                        }
                    }
                }
            }
        }
    }
}

extern "C" void kernel_launch(void* const* d_in, const int* in_sizes, int n_in,
                              void* d_out, int out_size, void* d_ws, size_t ws_size,
                              hipStream_t stream) {
    const float* x      = (const float*)d_in[0];
    const float* qkv_w  = (const float*)d_in[1];
    const float* qkv_b  = (const float*)d_in[2];
    const float* conv_w = (const float*)d_in[3];
    const float* conv_b = (const float*)d_in[4];
    float* out = (float*)d_out;

    __bf16* Bq = (__bf16*)d_ws;                       // 384*128 bf16
    __bf16* Bc = (__bf16*)((char*)d_ws + 98304);      // 128*128 bf16

    prep_kernel<<<256, 256, 0, stream>>>(qkv_w, conv_w, Bq, Bc);
    winattn_kernel<<<4096, 256, 0, stream>>>(x, qkv_b, conv_b, Bq, Bc, out);
}

// Round 6
// 579.395 us; speedup vs baseline: 1.2447x; 1.2447x over previous
//
#include <hip/hip_runtime.h>

// Fused 3D window attention (Swin-style) + 1x1 conv for MI355X (gfx950).
// One workgroup (256 thr = 4 waves) per 4x4x4 window; 4096 windows.
// Round-6: round-5 kernel UNCHANGED except LDS padded 32->40 KB to hard-cap
// residency at 4 blocks/CU. Mechanism (r5 post-mortem): the XCD swizzle makes
// each XCD run whole (D,H) row-slabs; per slab x+out L2 footprint ~2 MB. At
// 4 blocks/CU the cohort is ~4 slabs = at the 4 MB XCD-L2 edge (FETCH 136 MB,
// WRITE 283 MB). At 5 blocks/CU (r1/r5) it overflows -> zero W-neighbor reuse
// (FETCH 467 MB, WRITE 1150 MB, dur 2x). LDS is the only hard blocks/CU cap.
//  - QKV split into q-pass / v-pass / k-pass (acc peak 32, not 64)
//  - k-pass is the last x reader; after b2, k slots overwrite dead x (R0)
//  - QK^T phase A (nt=2,3 -> packed regs) BEFORE phase B (nt=0,1 -> LDS)
//  - deferred softmax normalization; exp2 with log2e folded into q scale
//  - wave-uniform anypad fast path; 3 barriers

#define NHEAD 8
#define HDIM 16
#define CCH 128
#define DD0 30
#define HH0 62
#define WW0 126
#define SD 7812      // HH0*WW0
#define SC 234360    // DD0*SD
#define QSCALE 0.3606737602f   // hd^-0.5 * log2(e) = 0.25 * 1.4426950409

typedef __bf16 bfx8 __attribute__((ext_vector_type(8)));
typedef float  fx4  __attribute__((ext_vector_type(4)));
typedef float  fx2  __attribute__((ext_vector_type(2)));

__device__ __forceinline__ fx4 MFMA(bfx8 a, bfx8 b, fx4 c) {
    return __builtin_amdgcn_mfma_f32_16x16x32_bf16(a, b, c, 0, 0, 0);
}
__device__ __forceinline__ fx4 fzero4() { fx4 v = {0.f, 0.f, 0.f, 0.f}; return v; }
__device__ __forceinline__ bfx8 bzero8() {
    bfx8 v;
    #pragma unroll
    for (int j = 0; j < 8; j++) v[j] = (__bf16)0.f;
    return v;
}
__device__ __forceinline__ unsigned pk2(float a, float b) {
    __bf16 ax = (__bf16)a, by = (__bf16)b;
    unsigned short ua = __builtin_bit_cast(unsigned short, ax);
    unsigned short ub = __builtin_bit_cast(unsigned short, by);
    return (unsigned)ua | ((unsigned)ub << 16);
}

// Cast weights to bf16. Row-major qkv_w[oc][c] / conv_w[o][c] IS the packed
// B-operand layout: B-frag lane reads 8 contiguous k at Bq[(n*16+kg)*8].
__global__ void prep_kernel(const float* __restrict__ qkv_w,
                            const float* __restrict__ conv_w,
                            __bf16* __restrict__ Bq, __bf16* __restrict__ Bc) {
    const int i = blockIdx.x * 256 + threadIdx.x;   // grid covers 65536 exactly
    if (i < 49152) Bq[i] = (__bf16)qkv_w[i];
    else            Bc[i - 49152] = (__bf16)conv_w[i - 49152];
}

__global__ __launch_bounds__(256, 5) void winattn_kernel(
    const float* __restrict__ x,
    const float* __restrict__ qkv_b,
    const float* __restrict__ conv_b,
    const __bf16* __restrict__ Bq,
    const __bf16* __restrict__ Bc,
    float* __restrict__ out)
{
    // 40 KB LDS (32 KB used + 8 KB pad = hard 4 blocks/CU cap):
    //  R0 [0,16K):  x-tile [64][128] -> k slots [8][64][16] -> P piece1 -> out stripes
    //  R1 [16K,32K): q slots [8][64][16] -> P piece0 staging
    __shared__ __align__(16) unsigned char lds_raw[40960];
    __bf16* R0 = (__bf16*)lds_raw;
    __bf16* R1 = (__bf16*)(lds_raw + 16384);

    const int tid  = threadIdx.x;
    const int wave = tid >> 6;
    const int lane = tid & 63;
    const int quad = lane >> 4;
    const int l15  = lane & 15;

    // XCD swizzle: blocks round-robin over 8 XCDs; give each XCD a contiguous
    // 512-window slab so W-adjacent windows (sharing lines) are L2-local.
    const int blk = blockIdx.x;
    const int wid = ((blk & 7) << 9) | (blk >> 3);
    const int Db = (wid >> 9) << 2;
    const int Hb = ((wid >> 5) & 15) << 2;
    const int Wb = (wid & 31) << 2;

    // pad-mask bit per token (token index == lane); token l = bd*16+bh*4+bw
    unsigned long long pmask;
    {
        const bool p = (Db + (lane >> 4) >= DD0) || (Hb + ((lane >> 2) & 3) >= HH0) ||
                       (Wb + (lane & 3) >= WW0);
        pmask = __ballot(p);
    }
    const bool anypad = (pmask != 0ULL);   // wave-uniform

    // ---- stage x window tile -> R0 bf16, swizzle phys_chunk = (c>>3) ^ (tok&15) ----
    {
        #pragma unroll
        for (int it = 0; it < 16; it++) {
            const int u = it * 256 + tid;          // (c, dh, wpair)
            const int wp = u & 1;
            const int dh = (u >> 1) & 15;
            const int c  = u >> 5;
            const int Dg = Db + (dh >> 2), Hg = Hb + (dh & 3);
            const bool valid = (Dg < DD0) && (Hg < HH0) && (wp == 0 || Wb < 124);
            fx2 v = {0.f, 0.f};
            if (valid) v = *(const fx2*)(x + c * SC + Dg * SD + Hg * WW0 + Wb + wp * 2);
            const int tok0 = dh * 4 + wp * 2;
            const int ch = c >> 3, cl = c & 7;
            R0[tok0 * 128 + ((ch ^ (tok0 & 15)) << 3) + cl] = (__bf16)v[0];
            const int tok1 = tok0 + 1;
            R0[tok1 * 128 + ((ch ^ (tok1 & 15)) << 3) + cl] = (__bf16)v[1];
        }
    }
    __syncthreads();   // b1

    unsigned vpk[2][4][2];   // v (head wave+4*hi) packed bf16: [hi][mt][r-pair]

    // ---- q-pass: q(w), q(w+4) -> R1 q slots (pre-scaled by 0.25*log2e) ----
    {
        fx4 acc[4][2];
        #pragma unroll
        for (int mt = 0; mt < 4; mt++)
            #pragma unroll
            for (int hi = 0; hi < 2; hi++) acc[mt][hi] = fzero4();
        #pragma unroll
        for (int ks = 0; ks < 4; ks++) {
            bfx8 a[4];
            #pragma unroll
            for (int mt = 0; mt < 4; mt++) {
                const int m = mt * 16 + l15;
                const int phys = (ks * 4 + quad) ^ (m & 15);
                a[mt] = *(const bfx8*)(R0 + m * 128 + phys * 8);
            }
            #pragma unroll
            for (int hi = 0; hi < 2; hi++) {
                const int col = (wave + hi * 4) * 16 + l15;
                const bfx8 bb = *(const bfx8*)(Bq + (col * 16 + ks * 4 + quad) * 8);
                #pragma unroll
                for (int mt = 0; mt < 4; mt++) acc[mt][hi] = MFMA(a[mt], bb, acc[mt][hi]);
            }
        }
        // q -> R1 slots (R1 untouched by staging: no barrier needed)
        #pragma unroll
        for (int hi = 0; hi < 2; hi++) {
            const int hh = wave + hi * 4;
            const float bias = qkv_b[hh * 16 + l15];
            #pragma unroll
            for (int mt = 0; mt < 4; mt++)
                #pragma unroll
                for (int r = 0; r < 4; r++) {
                    const int tok = mt * 16 + quad * 4 + r;
                    const int phys = (l15 >> 3) ^ ((tok >> 2) & 1);
                    R1[hh * 1024 + tok * 16 + phys * 8 + (l15 & 7)] =
                        (__bf16)((acc[mt][hi][r] + bias) * QSCALE);
                }
        }
    }

    // ---- v-pass: v(w), v(w+4) -> vpk registers ----
    {
        fx4 acc[4][2];
        #pragma unroll
        for (int mt = 0; mt < 4; mt++)
            #pragma unroll
            for (int hi = 0; hi < 2; hi++) acc[mt][hi] = fzero4();
        #pragma unroll
        for (int ks = 0; ks < 4; ks++) {
            bfx8 a[4];
            #pragma unroll
            for (int mt = 0; mt < 4; mt++) {
                const int m = mt * 16 + l15;
                const int phys = (ks * 4 + quad) ^ (m & 15);
                a[mt] = *(const bfx8*)(R0 + m * 128 + phys * 8);
            }
            #pragma unroll
            for (int hi = 0; hi < 2; hi++) {
                const int col = 256 + (wave + hi * 4) * 16 + l15;
                const bfx8 bb = *(const bfx8*)(Bq + (col * 16 + ks * 4 + quad) * 8);
                #pragma unroll
                for (int mt = 0; mt < 4; mt++) acc[mt][hi] = MFMA(a[mt], bb, acc[mt][hi]);
            }
        }
        #pragma unroll
        for (int hi = 0; hi < 2; hi++) {
            const float bias = qkv_b[256 + (wave + hi * 4) * 16 + l15];
            #pragma unroll
            for (int mt = 0; mt < 4; mt++) {
                vpk[hi][mt][0] = pk2(acc[mt][hi][0] + bias, acc[mt][hi][1] + bias);
                vpk[hi][mt][1] = pk2(acc[mt][hi][2] + bias, acc[mt][hi][3] + bias);
            }
        }
    }

    // ---- k-pass (last x reader): k(w), k(w+4) -> b2 -> R0 k slots ----
    {
        fx4 acc[4][2];
        #pragma unroll
        for (int mt = 0; mt < 4; mt++)
            #pragma unroll
            for (int hi = 0; hi < 2; hi++) acc[mt][hi] = fzero4();
        #pragma unroll
        for (int ks = 0; ks < 4; ks++) {
            bfx8 a[4];
            #pragma unroll
            for (int mt = 0; mt < 4; mt++) {
                const int m = mt * 16 + l15;
                const int phys = (ks * 4 + quad) ^ (m & 15);
                a[mt] = *(const bfx8*)(R0 + m * 128 + phys * 8);
            }
            #pragma unroll
            for (int hi = 0; hi < 2; hi++) {
                const int col = 128 + (wave + hi * 4) * 16 + l15;
                const bfx8 bb = *(const bfx8*)(Bq + (col * 16 + ks * 4 + quad) * 8);
                #pragma unroll
                for (int mt = 0; mt < 4; mt++) acc[mt][hi] = MFMA(a[mt], bb, acc[mt][hi]);
            }
        }
        __syncthreads();   // b2: all waves' x reads done; R0 becomes k slots
        #pragma unroll
        for (int hi = 0; hi < 2; hi++) {
            const int hh = wave + hi * 4;
            const float bias = qkv_b[128 + hh * 16 + l15];
            #pragma unroll
            for (int mt = 0; mt < 4; mt++)
                #pragma unroll
                for (int r = 0; r < 4; r++) {
                    const int tok = mt * 16 + quad * 4 + r;
                    const int phys = (l15 >> 3) ^ ((tok >> 2) & 1);
                    R0[hh * 1024 + tok * 16 + phys * 8 + (l15 & 7)] =
                        (__bf16)(acc[mt][hi][r] + bias);
                }
        }
    }
    // NO b3: q/k slots are wave-private; same-wave DS ops are in-order.

    // ---- attention: wave w handles heads w and w+4 (fully wave-private) ----
    // Phase A: nt=2,3 -> packed regs (k rows 32-63 consumed). Phase B: nt=0,1
    // -> LDS pieces (k rows 0-31 read before the kk piece write). PV half0,
    // stage pkS, PV half1. Deferred normalization on ovec.
    const int srcA = ((((quad << 1) + 0) & 3) << 4) | l15;
    const int srcB = ((((quad << 1) + 1) & 3) << 4) | l15;
    #pragma unroll
    for (int hi = 0; hi < 2; hi++) {
        const int hh = wave + hi * 4;
        __bf16* qs = R1 + hh * 1024;   // q slot -> P piece 0
        __bf16* kk = R0 + hh * 1024;   // k slot -> P piece 1 -> out stripe

        // A-frag from q slot (hd=16: quads 2,3 zero); qs dead after.
        bfx8 aq[4];
        #pragma unroll
        for (int mt = 0; mt < 4; mt++) {
            aq[mt] = bzero8();
            if (quad < 2) {
                const int m = mt * 16 + l15;
                const int phys = quad ^ ((m >> 2) & 1);
                aq[mt] = *(const bfx8*)(qs + m * 16 + phys * 8);
            }
        }

        float part[4][4];
        #pragma unroll
        for (int mt = 0; mt < 4; mt++)
            #pragma unroll
            for (int r = 0; r < 4; r++) part[mt][r] = 0.f;

        unsigned pkS[2][4][2];   // packed exp P for nt=2,3

        // phase A: nt = 2,3 -> regs (ALL reads of kk rows 32-63 happen here)
        #pragma unroll
        for (int ntq = 0; ntq < 2; ntq++) {
            const int nt = 2 + ntq;
            bfx8 bk = bzero8();
            if (quad < 2) {
                const int n = nt * 16 + l15;
                const int phys = quad ^ ((n >> 2) & 1);
                bk = *(const bfx8*)(kk + n * 16 + phys * 8);
            }
            fx4 lt[4];
            #pragma unroll
            for (int mt = 0; mt < 4; mt++) lt[mt] = MFMA(aq[mt], bk, fzero4());
            const unsigned cb = (unsigned)(pmask >> (nt * 16 + l15)) & 1u;
            #pragma unroll
            for (int mt = 0; mt < 4; mt++) {
                fx4 e;
                if (anypad) {
                    #pragma unroll
                    for (int r = 0; r < 4; r++) {
                        const unsigned rb =
                            (unsigned)(pmask >> (mt * 16 + quad * 4 + r)) & 1u;
                        e[r] = (rb ^ cb) ? 0.f : __builtin_amdgcn_exp2f(lt[mt][r]);
                    }
                } else {
                    #pragma unroll
                    for (int r = 0; r < 4; r++)
                        e[r] = __builtin_amdgcn_exp2f(lt[mt][r]);
                }
                #pragma unroll
                for (int r = 0; r < 4; r++) part[mt][r] += e[r];
                pkS[ntq][mt][0] = pk2(e[0], e[1]);
                pkS[ntq][mt][1] = pk2(e[2], e[3]);
            }
        }
        // phase B: nt = 0,1 -> stage into pieces (kk read precedes kk write
        // within this phase; rows 32-63 already consumed in phase A)
        #pragma unroll
        for (int nt = 0; nt < 2; nt++) {
            bfx8 bk = bzero8();
            if (quad < 2) {
                const int n = nt * 16 + l15;
                const int phys = quad ^ ((n >> 2) & 1);
                bk = *(const bfx8*)(kk + n * 16 + phys * 8);
            }
            fx4 lt[4];
            #pragma unroll
            for (int mt = 0; mt < 4; mt++) lt[mt] = MFMA(aq[mt], bk, fzero4());
            __bf16* piece = nt ? kk : qs;
            const unsigned cb = (unsigned)(pmask >> (nt * 16 + l15)) & 1u;
            #pragma unroll
            for (int mt = 0; mt < 4; mt++) {
                fx4 e;
                if (anypad) {
                    #pragma unroll
                    for (int r = 0; r < 4; r++) {
                        const unsigned rb =
                            (unsigned)(pmask >> (mt * 16 + quad * 4 + r)) & 1u;
                        e[r] = (rb ^ cb) ? 0.f : __builtin_amdgcn_exp2f(lt[mt][r]);
                    }
                } else {
                    #pragma unroll
                    for (int r = 0; r < 4; r++)
                        e[r] = __builtin_amdgcn_exp2f(lt[mt][r]);
                }
                #pragma unroll
                for (int r = 0; r < 4; r++) {
                    part[mt][r] += e[r];
                    const int tok = mt * 16 + quad * 4 + r;
                    const int phys = (l15 >> 3) ^ ((tok >> 2) & 1);
                    piece[tok * 16 + phys * 8 + (l15 & 7)] = (__bf16)e[r];
                }
            }
        }

        fx4 ovec[4];
        #pragma unroll
        for (int mt = 0; mt < 4; mt++) ovec[mt] = fzero4();

        #pragma unroll
        for (int half = 0; half < 2; half++) {
            if (half == 1) {
                // stage nt=2,3 pieces from pkS (after PV half0 reads; in-order DS)
                #pragma unroll
                for (int ntq = 0; ntq < 2; ntq++) {
                    __bf16* piece = ntq ? kk : qs;
                    #pragma unroll
                    for (int mt = 0; mt < 4; mt++)
                        #pragma unroll
                        for (int r = 0; r < 4; r++) {
                            const unsigned pr = pkS[ntq][mt][r >> 1];
                            const unsigned short hv =
                                (r & 1) ? (unsigned short)(pr >> 16)
                                        : (unsigned short)(pr & 0xffffu);
                            const int tok = mt * 16 + quad * 4 + r;
                            const int phys = (l15 >> 3) ^ ((tok >> 2) & 1);
                            piece[tok * 16 + phys * 8 + (l15 & 7)] =
                                __builtin_bit_cast(__bf16, hv);
                        }
                }
            }
            // PV half on unnormalized P; V B-frag built by shuffles from vpk.
            // bv[j] = v[half*32 + quad*8 + j][l15]
            const unsigned a00 = (unsigned)__shfl((int)vpk[hi][half * 2 + 0][0], srcA);
            const unsigned a01 = (unsigned)__shfl((int)vpk[hi][half * 2 + 0][1], srcA);
            const unsigned a10 = (unsigned)__shfl((int)vpk[hi][half * 2 + 1][0], srcA);
            const unsigned a11 = (unsigned)__shfl((int)vpk[hi][half * 2 + 1][1], srcA);
            const unsigned b00 = (unsigned)__shfl((int)vpk[hi][half * 2 + 0][0], srcB);
            const unsigned b01 = (unsigned)__shfl((int)vpk[hi][half * 2 + 0][1], srcB);
            const unsigned b10 = (unsigned)__shfl((int)vpk[hi][half * 2 + 1][0], srcB);
            const unsigned b11 = (unsigned)__shfl((int)vpk[hi][half * 2 + 1][1], srcB);
            const bool mhi = quad >= 2;
            uint4 uv;
            uv.x = mhi ? a10 : a00;
            uv.y = mhi ? a11 : a01;
            uv.z = mhi ? b10 : b00;
            uv.w = mhi ? b11 : b01;
            const bfx8 bv = __builtin_bit_cast(bfx8, uv);
            #pragma unroll
            for (int mt = 0; mt < 4; mt++) {
                const int m = mt * 16 + l15;
                const int phys = (quad & 1) ^ ((m >> 2) & 1);
                const bfx8 ap = *(const bfx8*)(((quad >> 1) ? kk : qs) + m * 16 + phys * 8);
                ovec[mt] = MFMA(ap, bv, ovec[mt]);
            }
        }
        // row-sum reduce (over l15 lanes) + deferred normalize + stripe write.
        // Stripe for head hh overlays its own k slot (dead; wave-private).
        #pragma unroll
        for (int mt = 0; mt < 4; mt++)
            #pragma unroll
            for (int r = 0; r < 4; r++) {
                float s = part[mt][r];
                s += __shfl_xor(s, 1);
                s += __shfl_xor(s, 2);
                s += __shfl_xor(s, 4);
                s += __shfl_xor(s, 8);
                const float rinv = __builtin_amdgcn_rcpf(s);
                const int tok = mt * 16 + quad * 4 + r;
                const int phys = (l15 >> 3) ^ ((tok >> 2) & 1);
                kk[tok * 16 + phys * 8 + (l15 & 7)] = (__bf16)(ovec[mt][r] * rinv);
            }
    }
    __syncthreads();   // b4: all stripes written; R0 = attn-out [8 stripes][64][16]

    // ---- 1x1 conv: (64x128)@(128x128); wave owns 32 cols; store from C-layout ----
    {
        fx4 cacc[4][2];
        #pragma unroll
        for (int mt = 0; mt < 4; mt++)
            #pragma unroll
            for (int nt = 0; nt < 2; nt++) cacc[mt][nt] = fzero4();
        #pragma unroll
        for (int ks = 0; ks < 4; ks++) {
            const int kg = ks * 4 + quad;          // channel chunk = head stripe kg>>1
            bfx8 a[4];
            #pragma unroll
            for (int mt = 0; mt < 4; mt++) {
                const int m = mt * 16 + l15;
                const int phys = (kg & 1) ^ ((m >> 2) & 1);
                a[mt] = *(const bfx8*)(R0 + (kg >> 1) * 1024 + m * 16 + phys * 8);
            }
            #pragma unroll
            for (int nt = 0; nt < 2; nt++) {
                const int o = wave * 32 + nt * 16 + l15;
                const bfx8 bb = *(const bfx8*)(Bc + (o * 16 + kg) * 8);
                #pragma unroll
                for (int mt = 0; mt < 4; mt++) cacc[mt][nt] = MFMA(a[mt], bb, cacc[mt][nt]);
            }
        }
        // C-layout: cacc[mt][nt][r] = out[o=..][D=Db+mt][H=Hb+quad][W=Wb+r]
        #pragma unroll
        for (int nt = 0; nt < 2; nt++) {
            const int o = wave * 32 + nt * 16 + l15;
            const float cb = conv_b[o];
            #pragma unroll
            for (int mt = 0; mt < 4; mt++) {
                if (Db + mt < DD0) {
                    const int Hg = Hb + quad;
                    if (Hg < HH0) {
                        const int base = o * SC + (Db + mt) * SD + Hg * WW0 + Wb;
                        fx2 w0 = {cacc[mt][nt][0] + cb, cacc[mt][nt][1] + cb};
                        *(fx2*)(out + base) = w0;
                        if (Wb < 124) {
                            fx2 w1 = {cacc[mt][nt][2] + cb, cacc[mt][nt][3] + cb};
                            *(fx2*)(out + base + 2) = w1;
                        }
                    }
                }
            }
        }
    }
}

extern "C" void kernel_launch(void* const* d_in, const int* in_sizes, int n_in,
                              void* d_out, int out_size, void* d_ws, size_t ws_size,
                              hipStream_t stream) {
    const float* x      = (const float*)d_in[0];
    const float* qkv_w  = (const float*)d_in[1];
    const float* qkv_b  = (const float*)d_in[2];
    const float* conv_w = (const float*)d_in[3];
    const float* conv_b = (const float*)d_in[4];
    float* out = (float*)d_out;

    __bf16* Bq = (__bf16*)d_ws;                       // 384*128 bf16
    __bf16* Bc = (__bf16*)((char*)d_ws + 98304);      // 128*128 bf16

    prep_kernel<<<256, 256, 0, stream>>>(qkv_w, conv_w, Bq, Bc);
    winattn_kernel<<<4096, 256, 0, stream>>>(x, qkv_b, conv_b, Bq, Bc, out);
}

// Round 7
// 399.415 us; speedup vs baseline: 1.8056x; 1.4506x over previous
//
#include <hip/hip_runtime.h>

// Fused 3D window attention (Swin-style) + 1x1 conv for MI355X (gfx950).
// Round-7 = round-2 shell (best measured: 284.6 us) + round-1-proven slim
// attention internals. Shell: TWO W-adjacent 4x4x4 windows per 512-thread
// block (8 waves), 64 KB LDS -> hard 2 blocks/CU (the L2-safe residency:
// 128 windows/XCD = 4 row-slabs ~ 4MB; r5/r6 showed more thrashes, fewer
// exposes latency). Slim internals (all verified in r1/r5 runs):
//  - swapped QK^T (S^T in regs): in-lane row sums + 2 shfls (vs 64 shfls)
//  - deferred softmax normalization (rinv on 16 ovec elems, not 128 P elems)
//  - uint2-packed P-piece staging (8 DS writes/head vs 32)
//  - phase A (nt=2,3 -> regs) before phase B (nt=0,1 -> LDS): k-slot reads
//    complete before piece writes clobber (r3 bug fixed in r5)
//  - exp2 with log2e folded into q scale; wave-uniform anypad fast path
//  - b3 removed (q/k slots wave-private; same-wave DS ops are in-order)

#define NHEAD 8
#define HDIM 16
#define CCH 128
#define DD0 30
#define HH0 62
#define WW0 126
#define SD 7812      // HH0*WW0
#define SC 234360    // DD0*SD
#define QSCALE 0.3606737602f   // hd^-0.5 * log2(e) = 0.25 * 1.4426950409

typedef __bf16 bfx8 __attribute__((ext_vector_type(8)));
typedef float  fx4  __attribute__((ext_vector_type(4)));
typedef float  fx2  __attribute__((ext_vector_type(2)));

__device__ __forceinline__ fx4 MFMA(bfx8 a, bfx8 b, fx4 c) {
    return __builtin_amdgcn_mfma_f32_16x16x32_bf16(a, b, c, 0, 0, 0);
}
__device__ __forceinline__ fx4 fzero4() { fx4 v = {0.f, 0.f, 0.f, 0.f}; return v; }
__device__ __forceinline__ bfx8 bzero8() {
    bfx8 v;
    #pragma unroll
    for (int j = 0; j < 8; j++) v[j] = (__bf16)0.f;
    return v;
}
__device__ __forceinline__ unsigned pk2(float a, float b) {
    __bf16 ax = (__bf16)a, by = (__bf16)b;
    unsigned short ua = __builtin_bit_cast(unsigned short, ax);
    unsigned short ub = __builtin_bit_cast(unsigned short, by);
    return (unsigned)ua | ((unsigned)ub << 16);
}

// Cast weights to bf16. Row-major qkv_w[oc][c] / conv_w[o][c] IS the packed
// B-operand layout: B-frag lane reads 8 contiguous k at Bq[(n*16+kg)*8].
__global__ void prep_kernel(const float* __restrict__ qkv_w,
                            const float* __restrict__ conv_w,
                            __bf16* __restrict__ Bq, __bf16* __restrict__ Bc) {
    const int i = blockIdx.x * 256 + threadIdx.x;   // grid covers 65536 exactly
    if (i < 49152) Bq[i] = (__bf16)qkv_w[i];
    else            Bc[i - 49152] = (__bf16)conv_w[i - 49152];
}

__global__ __launch_bounds__(512, 4) void winattn_kernel(
    const float* __restrict__ x,
    const float* __restrict__ qkv_b,
    const float* __restrict__ conv_b,
    const __bf16* __restrict__ Bq,
    const __bf16* __restrict__ Bc,
    float* __restrict__ out)
{
    // 64 KB LDS, 32 KB per window:
    //  win*32K + [0,16K):  x-tile [64][128] -> q slots [8][64][16] -> P piece0 -> out stripes
    //  win*32K + [16K,32K): k slots [8][64][16] -> P piece1
    __shared__ __align__(16) unsigned char lds_raw[65536];

    const int tid   = threadIdx.x;
    const int wave8 = tid >> 6;       // 0..7
    const int win   = wave8 >> 2;     // 0: window A (Wb), 1: window B (Wb+4)
    const int wave  = wave8 & 3;      // role within window
    const int lane  = tid & 63;
    const int quad  = lane >> 4;
    const int l15   = lane & 15;

    __bf16* ldsQ = (__bf16*)(lds_raw + win * 32768);           // also x-tile
    __bf16* ldsK = (__bf16*)(lds_raw + win * 32768 + 16384);

    // XCD swizzle: blocks round-robin over 8 XCDs; give each XCD a contiguous
    // 256-pair slab so W-adjacent pairs are L2-local.
    const int blk = blockIdx.x;                    // 2048 blocks
    const int wid = ((blk & 7) << 8) | (blk >> 3); // (d:8, h:16, wpair:16)
    const int Db = (wid >> 8) << 2;
    const int Hb = ((wid >> 4) & 15) << 2;
    const int Wp = (wid & 15) << 3;                // pair base W (0..120)
    const int Wb = Wp + win * 4;                   // this wave's window W base

    // pad-mask bit per token (token index == lane); token l = bd*16+bh*4+bw
    unsigned long long pmask;
    {
        const bool p = (Db + (lane >> 4) >= DD0) || (Hb + ((lane >> 2) & 3) >= HH0) ||
                       (Wb + (lane & 3) >= WW0);
        pmask = __ballot(p);
    }
    const bool anypad = (pmask != 0ULL);   // wave-uniform (win uniform per wave)

    // ---- stage x pair-tile -> bf16, swizzle phys_chunk = (c>>3) ^ (tok&15) ----
    // u = (c:128, dh:16, wq:4); lanes 0..3 read 32B contiguous (both windows).
    {
        #pragma unroll
        for (int it = 0; it < 16; it++) {
            const int u = it * 512 + tid;
            const int wq = u & 3;                  // fx2 index across the 8 W
            const int dh = (u >> 2) & 15;
            const int c  = u >> 6;
            const int Dg = Db + (dh >> 2), Hg = Hb + (dh & 3);
            const int Wg = Wp + wq * 2;
            fx2 v = {0.f, 0.f};
            if ((Dg < DD0) && (Hg < HH0) && (Wg < WW0))
                v = *(const fx2*)(x + c * SC + Dg * SD + Hg * WW0 + Wg);
            __bf16* R0 = (__bf16*)(lds_raw + (wq >> 1) * 32768);   // target window
            const int t0 = dh * 4 + (wq & 1) * 2;
            const int ch = c >> 3, cl = c & 7;
            R0[(t0 + 0) * 128 + ((ch ^ ((t0 + 0) & 15)) << 3) + cl] = (__bf16)v[0];
            R0[(t0 + 1) * 128 + ((ch ^ ((t0 + 1) & 15)) << 3) + cl] = (__bf16)v[1];
        }
    }
    __syncthreads();   // b1

    unsigned vpk[2][4][2];   // v (head wave+4*hi) packed bf16: [hi][mt][r-pair]

    // ---- QKV group 0: k(w), k(w+4), v(w), v(w+4)  (wave-private heads) ----
    {
        fx4 acc[4][4];
        #pragma unroll
        for (int mt = 0; mt < 4; mt++)
            #pragma unroll
            for (int j = 0; j < 4; j++) acc[mt][j] = fzero4();
        #pragma unroll
        for (int ks = 0; ks < 4; ks++) {
            bfx8 a[4];
            #pragma unroll
            for (int mt = 0; mt < 4; mt++) {
                const int m = mt * 16 + l15;
                const int phys = (ks * 4 + quad) ^ (m & 15);
                a[mt] = *(const bfx8*)(ldsQ + m * 128 + phys * 8);
            }
            #pragma unroll
            for (int j = 0; j < 4; j++) {
                const int col = (1 + (j >> 1)) * 128 + (wave + (j & 1) * 4) * 16 + l15;
                const bfx8 bb = *(const bfx8*)(Bq + (col * 16 + ks * 4 + quad) * 8);
                #pragma unroll
                for (int mt = 0; mt < 4; mt++) acc[mt][j] = MFMA(a[mt], bb, acc[mt][j]);
            }
        }
        // k -> ldsK slots (no conflict with x in ldsQ: no barrier needed)
        #pragma unroll
        for (int j = 0; j < 2; j++) {
            const int hh = wave + j * 4;
            const float bias = qkv_b[128 + hh * 16 + l15];
            #pragma unroll
            for (int mt = 0; mt < 4; mt++)
                #pragma unroll
                for (int r = 0; r < 4; r++) {
                    const int tok = mt * 16 + quad * 4 + r;
                    const int phys = (l15 >> 3) ^ ((tok >> 2) & 1);
                    ldsK[hh * 1024 + tok * 16 + phys * 8 + (l15 & 7)] =
                        (__bf16)(acc[mt][j][r] + bias);
                }
        }
        // v -> registers, packed bf16
        #pragma unroll
        for (int hi = 0; hi < 2; hi++) {
            const float bias = qkv_b[256 + (wave + hi * 4) * 16 + l15];
            #pragma unroll
            for (int mt = 0; mt < 4; mt++) {
                vpk[hi][mt][0] = pk2(acc[mt][2 + hi][0] + bias, acc[mt][2 + hi][1] + bias);
                vpk[hi][mt][1] = pk2(acc[mt][2 + hi][2] + bias, acc[mt][2 + hi][3] + bias);
            }
        }
    }

    // ---- QKV group 1: q(w), q(w+4), pre-scaled by 0.25*log2e ----
    {
        fx4 acc[4][2];
        #pragma unroll
        for (int mt = 0; mt < 4; mt++)
            #pragma unroll
            for (int hi = 0; hi < 2; hi++) acc[mt][hi] = fzero4();
        #pragma unroll
        for (int ks = 0; ks < 4; ks++) {
            bfx8 a[4];
            #pragma unroll
            for (int mt = 0; mt < 4; mt++) {
                const int m = mt * 16 + l15;
                const int phys = (ks * 4 + quad) ^ (m & 15);
                a[mt] = *(const bfx8*)(ldsQ + m * 128 + phys * 8);
            }
            #pragma unroll
            for (int hi = 0; hi < 2; hi++) {
                const int col = (wave + hi * 4) * 16 + l15;
                const bfx8 bb = *(const bfx8*)(Bq + (col * 16 + ks * 4 + quad) * 8);
                #pragma unroll
                for (int mt = 0; mt < 4; mt++) acc[mt][hi] = MFMA(a[mt], bb, acc[mt][hi]);
            }
        }
        __syncthreads();   // b2: all x-tile reads done; ldsQ becomes q slots
        #pragma unroll
        for (int hi = 0; hi < 2; hi++) {
            const int hh = wave + hi * 4;
            const float bias = qkv_b[hh * 16 + l15];
            #pragma unroll
            for (int mt = 0; mt < 4; mt++)
                #pragma unroll
                for (int r = 0; r < 4; r++) {
                    const int tok = mt * 16 + quad * 4 + r;
                    const int phys = (l15 >> 3) ^ ((tok >> 2) & 1);
                    ldsQ[hh * 1024 + tok * 16 + phys * 8 + (l15 & 7)] =
                        (__bf16)((acc[mt][hi][r] + bias) * QSCALE);
                }
        }
    }
    // NO b3: q/k slots are wave-private; same-wave DS ops are in-order.

    // ---- attention (swapped QK^T): wave w handles heads w and w+4 ----
    // lt = MFMA(k_frag, q_frag): lane holds S[q = 16mt+l15][k = 16nt+quad*4+r].
    // In-lane row sums + 2 shfls; deferred normalization on ovec.
    const int srcA = ((((quad << 1) + 0) & 3) << 4) | l15;
    const int srcB = ((((quad << 1) + 1) & 3) << 4) | l15;
    const int rsrc = lane & 48;
    #pragma unroll
    for (int hi = 0; hi < 2; hi++) {
        const int hh = wave + hi * 4;
        __bf16* qs = ldsQ + hh * 1024;   // q slot -> P piece 0 -> out stripe
        __bf16* kk = ldsK + hh * 1024;   // k slot -> P piece 1

        // B-frag: q rows m = 16mt + l15 (hd=16 -> quads 2,3 zero). qs dead after.
        bfx8 bq[4];
        #pragma unroll
        for (int mt = 0; mt < 4; mt++) {
            bq[mt] = bzero8();
            if (quad < 2) {
                const int m = mt * 16 + l15;
                const int phys = quad ^ ((m >> 2) & 1);
                bq[mt] = *(const bfx8*)(qs + m * 16 + phys * 8);
            }
        }

        unsigned cb4[4];
        #pragma unroll
        for (int mt = 0; mt < 4; mt++)
            cb4[mt] = (unsigned)(pmask >> (mt * 16 + l15)) & 1u;

        float sums[4] = {0.f, 0.f, 0.f, 0.f};
        unsigned pkS[2][4][2];   // packed exp P for nt = 2,3

        // phase A: nt = 2,3 -> regs (ALL reads of kk rows 32-63 happen here)
        #pragma unroll
        for (int ntq = 0; ntq < 2; ntq++) {
            const int nt = 2 + ntq;
            bfx8 ak = bzero8();
            if (quad < 2) {
                const int n = nt * 16 + l15;
                const int phys = quad ^ ((n >> 2) & 1);
                ak = *(const bfx8*)(kk + n * 16 + phys * 8);
            }
            fx4 lt[4];
            #pragma unroll
            for (int mt = 0; mt < 4; mt++) lt[mt] = MFMA(ak, bq[mt], fzero4());
            const unsigned rb4 = (unsigned)(pmask >> (nt * 16 + quad * 4));
            #pragma unroll
            for (int mt = 0; mt < 4; mt++) {
                fx4 e;
                if (anypad) {
                    #pragma unroll
                    for (int r = 0; r < 4; r++) {
                        const unsigned msk = ((rb4 >> r) ^ cb4[mt]) & 1u;
                        e[r] = msk ? 0.f : __builtin_amdgcn_exp2f(lt[mt][r]);
                    }
                } else {
                    #pragma unroll
                    for (int r = 0; r < 4; r++)
                        e[r] = __builtin_amdgcn_exp2f(lt[mt][r]);
                }
                sums[mt] += (e[0] + e[1]) + (e[2] + e[3]);
                pkS[ntq][mt][0] = pk2(e[0], e[1]);
                pkS[ntq][mt][1] = pk2(e[2], e[3]);
            }
        }
        // phase B: nt = 0,1 -> stage into pieces as uint2 (kk rows 0-31 read
        // before the kk piece write; rows 32-63 already consumed in phase A)
        #pragma unroll
        for (int nt = 0; nt < 2; nt++) {
            bfx8 ak = bzero8();
            if (quad < 2) {
                const int n = nt * 16 + l15;
                const int phys = quad ^ ((n >> 2) & 1);
                ak = *(const bfx8*)(kk + n * 16 + phys * 8);
            }
            fx4 lt[4];
            #pragma unroll
            for (int mt = 0; mt < 4; mt++) lt[mt] = MFMA(ak, bq[mt], fzero4());
            const unsigned rb4 = (unsigned)(pmask >> (nt * 16 + quad * 4));
            __bf16* piece = nt ? kk : qs;
            #pragma unroll
            for (int mt = 0; mt < 4; mt++) {
                fx4 e;
                if (anypad) {
                    #pragma unroll
                    for (int r = 0; r < 4; r++) {
                        const unsigned msk = ((rb4 >> r) ^ cb4[mt]) & 1u;
                        e[r] = msk ? 0.f : __builtin_amdgcn_exp2f(lt[mt][r]);
                    }
                } else {
                    #pragma unroll
                    for (int r = 0; r < 4; r++)
                        e[r] = __builtin_amdgcn_exp2f(lt[mt][r]);
                }
                sums[mt] += (e[0] + e[1]) + (e[2] + e[3]);
                const int m = mt * 16 + l15;
                const int addr = m * 16 + (((quad >> 1) ^ ((m >> 2) & 1)) << 3) +
                                 ((quad & 1) << 2);
                uint2 wv;
                wv.x = pk2(e[0], e[1]);
                wv.y = pk2(e[2], e[3]);
                *(uint2*)(piece + addr) = wv;
            }
        }

        // row sums: in-lane partial done; reduce across the 4 quads (same l15)
        #pragma unroll
        for (int mt = 0; mt < 4; mt++) {
            float s = sums[mt];
            s += __shfl_xor(s, 16);
            s += __shfl_xor(s, 32);
            sums[mt] = __builtin_amdgcn_rcpf(s);   // rinv for row m = 16mt + l15
        }

        // P@V on unnormalized P; V B-frag built by shuffles from vpk.
        fx4 ovec[4];
        #pragma unroll
        for (int mt = 0; mt < 4; mt++) ovec[mt] = fzero4();
        #pragma unroll
        for (int half = 0; half < 2; half++) {
            if (half == 1) {
                // stage nt=2,3 pieces from pkS (after PV half0 reads; in-order DS)
                #pragma unroll
                for (int ntq = 0; ntq < 2; ntq++) {
                    __bf16* piece = ntq ? kk : qs;
                    #pragma unroll
                    for (int mt = 0; mt < 4; mt++) {
                        const int m = mt * 16 + l15;
                        const int addr = m * 16 + (((quad >> 1) ^ ((m >> 2) & 1)) << 3) +
                                         ((quad & 1) << 2);
                        uint2 wv;
                        wv.x = pkS[ntq][mt][0];
                        wv.y = pkS[ntq][mt][1];
                        *(uint2*)(piece + addr) = wv;
                    }
                }
            }
            // bv[j] = v[half*32 + quad*8 + j][l15]
            const unsigned a00 = (unsigned)__shfl((int)vpk[hi][half * 2 + 0][0], srcA);
            const unsigned a01 = (unsigned)__shfl((int)vpk[hi][half * 2 + 0][1], srcA);
            const unsigned a10 = (unsigned)__shfl((int)vpk[hi][half * 2 + 1][0], srcA);
            const unsigned a11 = (unsigned)__shfl((int)vpk[hi][half * 2 + 1][1], srcA);
            const unsigned b00 = (unsigned)__shfl((int)vpk[hi][half * 2 + 0][0], srcB);
            const unsigned b01 = (unsigned)__shfl((int)vpk[hi][half * 2 + 0][1], srcB);
            const unsigned b10 = (unsigned)__shfl((int)vpk[hi][half * 2 + 1][0], srcB);
            const unsigned b11 = (unsigned)__shfl((int)vpk[hi][half * 2 + 1][1], srcB);
            const bool mhi = quad >= 2;
            uint4 uv;
            uv.x = mhi ? a10 : a00;
            uv.y = mhi ? a11 : a01;
            uv.z = mhi ? b10 : b00;
            uv.w = mhi ? b11 : b01;
            const bfx8 bv = __builtin_bit_cast(bfx8, uv);
            #pragma unroll
            for (int mt = 0; mt < 4; mt++) {
                const int m = mt * 16 + l15;
                const int phys = (quad & 1) ^ ((m >> 2) & 1);
                const bfx8 ap = *(const bfx8*)(((quad >> 1) ? kk : qs) + m * 16 + phys * 8);
                ovec[mt] = MFMA(ap, bv, ovec[mt]);
            }
        }
        // deferred normalization + attn-out head stripe -> q slot (wave-private)
        #pragma unroll
        for (int mt = 0; mt < 4; mt++)
            #pragma unroll
            for (int r = 0; r < 4; r++) {
                const float rv = __shfl(sums[mt], rsrc | (quad * 4 + r));
                const int tok = mt * 16 + quad * 4 + r;
                const int phys = (l15 >> 3) ^ ((tok >> 2) & 1);
                qs[tok * 16 + phys * 8 + (l15 & 7)] = (__bf16)(ovec[mt][r] * rv);
            }
    }
    __syncthreads();   // b4: all stripes written; ldsQ = attn-out [8 stripes][64][16]

    // ---- 1x1 conv: (64x128)@(128x128); wave owns 32 cols; store from C-layout ----
    // Windows A/B of this block store W=[Wb,Wb+4) each -> 32B sectors fully
    // dirtied inside one block on one XCD (structural write merging).
    {
        fx4 cacc[4][2];
        #pragma unroll
        for (int mt = 0; mt < 4; mt++)
            #pragma unroll
            for (int nt = 0; nt < 2; nt++) cacc[mt][nt] = fzero4();
        #pragma unroll
        for (int ks = 0; ks < 4; ks++) {
            const int kg = ks * 4 + quad;          // channel chunk = head stripe kg>>1
            bfx8 a[4];
            #pragma unroll
            for (int mt = 0; mt < 4; mt++) {
                const int m = mt * 16 + l15;
                const int phys = (kg & 1) ^ ((m >> 2) & 1);
                a[mt] = *(const bfx8*)(ldsQ + (kg >> 1) * 1024 + m * 16 + phys * 8);
            }
            #pragma unroll
            for (int nt = 0; nt < 2; nt++) {
                const int o = wave * 32 + nt * 16 + l15;
                const bfx8 bb = *(const bfx8*)(Bc + (o * 16 + kg) * 8);
                #pragma unroll
                for (int mt = 0; mt < 4; mt++) cacc[mt][nt] = MFMA(a[mt], bb, cacc[mt][nt]);
            }
        }
        // C-layout: cacc[mt][nt][r] = out[o=..][D=Db+mt][H=Hb+quad][W=Wb+r]
        #pragma unroll
        for (int nt = 0; nt < 2; nt++) {
            const int o = wave * 32 + nt * 16 + l15;
            const float cb = conv_b[o];
            #pragma unroll
            for (int mt = 0; mt < 4; mt++) {
                if (Db + mt < DD0) {
                    const int Hg = Hb + quad;
                    if (Hg < HH0) {
                        const int base = o * SC + (Db + mt) * SD + Hg * WW0 + Wb;
                        fx2 w0 = {cacc[mt][nt][0] + cb, cacc[mt][nt][1] + cb};
                        *(fx2*)(out + base) = w0;
                        if (Wb < 124) {
                            fx2 w1 = {cacc[mt][nt][2] + cb, cacc[mt][nt][3] + cb};
                            *(fx2*)(out + base + 2) = w1;
                        }
                    }
                }
            }
        }
    }
}

extern "C" void kernel_launch(void* const* d_in, const int* in_sizes, int n_in,
                              void* d_out, int out_size, void* d_ws, size_t ws_size,
                              hipStream_t stream) {
    const float* x      = (const float*)d_in[0];
    const float* qkv_w  = (const float*)d_in[1];
    const float* qkv_b  = (const float*)d_in[2];
    const float* conv_w = (const float*)d_in[3];
    const float* conv_b = (const float*)d_in[4];
    float* out = (float*)d_out;

    __bf16* Bq = (__bf16*)d_ws;                       // 384*128 bf16
    __bf16* Bc = (__bf16*)((char*)d_ws + 98304);      // 128*128 bf16

    prep_kernel<<<256, 256, 0, stream>>>(qkv_w, conv_w, Bq, Bc);
    winattn_kernel<<<2048, 512, 0, stream>>>(x, qkv_b, conv_b, Bq, Bc, out);
}